// Round 3
// baseline (235.035 us; speedup 1.0000x reference)
//
#include <hip/hip_runtime.h>

// YOLO loss, forward only. pred/target: (16384, 7, 7, 30) fp32, out: scalar fp32.
// S=7, B=2, CLS=20, N=30, LAMBDA_COORD=5, LAMBDA_NOOBJ=0.5, BATCH=16384.
// NOTE: reference conf_loc = arange(B)*B+4 = [4,6] (not [4,9]) — mirrored here.
//
// R2: fully-coalesced single global pass + compact LDS.
//   R1 post-mortem: 120 B inter-lane stride -> each wave load touched ~60
//   cache lines (8x L1-transaction amplification) -> TA-limited at ~75 us.
//   R0 post-mortem: coalesced but 61 KB LDS -> 2 blocks/CU -> latency-bound.
//   Here: coalesced float2 pass decodes (cell,slot) via magic-div, scatters
//   only p[0..9] / t[0..6] into padded LDS (19.5 KB -> ~8 blocks/CU), and
//   accumulates the class term sum_{k>=10}(p-t)^2 inline via ds_add_f32.

#define TPB 256
#define NPER 30
#define R_TOTAL (16384 * 7 * 7)    // 802816 cells
#define NBLOCKS (R_TOTAL / TPB)    // 3136
#define PB_STRIDE 11               // 10 box/conf floats + 1 pad (odd stride: no bank conflict)
#define TB_STRIDE 7                // t[0..6], odd stride

__global__ __launch_bounds__(TPB, 4) void yolo_loss_kernel(
    const float* __restrict__ pred, const float* __restrict__ target,
    float* __restrict__ out)
{
    __shared__ float pb[TPB * PB_STRIDE];   // 11264 B
    __shared__ float tb[TPB * TB_STRIDE];   //  7168 B
    __shared__ float cls[TPB];              //  1024 B
    __shared__ float red[TPB / 64];

    const int tid = threadIdx.x;
    cls[tid] = 0.0f;
    __syncthreads();

    // ---- Phase 1: coalesced float2 sweep over the block's 256-cell tile ----
    const size_t base = (size_t)blockIdx.x * (TPB * NPER);
    const float2* gp = (const float2*)(pred + base);
    const float2* gt = (const float2*)(target + base);

    #pragma unroll
    for (int k = 0; k < (TPB * NPER) / (2 * TPB); k++) {   // 15 iterations
        int F = tid + k * TPB;                  // float2 index within tile
        float2 vp = gp[F];
        float2 vt = gt[F];
        unsigned f0 = 2u * (unsigned)F;         // float index, 0..7678
        unsigned c0 = (f0 * 34953u) >> 20;      // f0 / 30  (exact for f0 < 74898)
        int s0 = (int)(f0 - c0 * 30u);          // f0 % 30
        int s1 = s0 + 1;
        unsigned c1 = c0;
        if (s1 == 30) { s1 = 0; c1 = c0 + 1; }

        // scatter responsible-box + conf fields
        if (s0 < 10) pb[c0 * PB_STRIDE + s0] = vp.x;
        if (s1 < 10) pb[c1 * PB_STRIDE + s1] = vp.y;
        if (s0 < 7)  tb[c0 * TB_STRIDE + s0] = vt.x;
        if (s1 < 7)  tb[c1 * TB_STRIDE + s1] = vt.y;

        // class term: sum over slots 10..29 of (p-t)^2
        float d0 = vp.x - vt.x;
        float d1 = vp.y - vt.y;
        if (c1 == c0) {
            if (s1 >= 10) {
                float e = d1 * d1;
                if (s0 >= 10) e += d0 * d0;
                atomicAdd(&cls[c0], e);
            }
        } else {
            // s0 == 29 (always class), s1 == 0 (never class)
            atomicAdd(&cls[c0], d0 * d0);
        }
    }
    __syncthreads();

    // ---- Phase 2: one cell per thread, all operands from LDS ----
    const float* p = &pb[tid * PB_STRIDE];
    const float* t = &tb[tid * TB_STRIDE];

    float sum = 0.0f;
    const float t4 = t[4];
    if (t4 == 0.0f) {
        // noobj: 0.5 * sum over conf_loc=[4,6] of (p-t)^2
        float d4 = p[4] - t[4];
        float d6 = p[6] - t[6];
        sum = 0.5f * (d4 * d4 + d6 * d6);
    } else if (t4 == 1.0f) {
        float tx1 = t[0] - t[2] * 0.5f, ty1 = t[1] - t[3] * 0.5f;
        float tx2 = t[0] + t[2] * 0.5f, ty2 = t[1] + t[3] * 0.5f;
        float area2 = (tx2 - tx1) * (ty2 - ty1);

        // box 0
        float ax1 = p[0] - p[2] * 0.5f, ay1 = p[1] - p[3] * 0.5f;
        float ax2 = p[0] + p[2] * 0.5f, ay2 = p[1] + p[3] * 0.5f;
        float w0 = fmaxf(fminf(ax2, tx2) - fmaxf(ax1, tx1), 0.0f);
        float h0 = fmaxf(fminf(ay2, ty2) - fmaxf(ay1, ty1), 0.0f);
        float inter0 = w0 * h0;
        float uni0 = (ax2 - ax1) * (ay2 - ay1) + area2 - inter0;
        float iou0 = (uni0 > 0.0f) ? (inter0 / uni0) : 0.0f;

        // box 1
        float bx1 = p[5] - p[7] * 0.5f, by1 = p[6] - p[8] * 0.5f;
        float bx2 = p[5] + p[7] * 0.5f, by2 = p[6] + p[8] * 0.5f;
        float w1 = fmaxf(fminf(bx2, tx2) - fmaxf(bx1, tx1), 0.0f);
        float h1 = fmaxf(fminf(by2, ty2) - fmaxf(by1, ty1), 0.0f);
        float inter1 = w1 * h1;
        float uni1 = (bx2 - bx1) * (by2 - by1) + area2 - inter1;
        float iou1 = (uni1 > 0.0f) ? (inter1 / uni1) : 0.0f;

        // argmax over 2 -> first max index on ties
        bool j1 = (iou1 > iou0);
        float max_iou = fmaxf(iou0, iou1);
        float r0 = j1 ? p[5] : p[0];
        float r1 = j1 ? p[6] : p[1];
        float r2 = j1 ? p[7] : p[2];
        float r3 = j1 ? p[8] : p[3];
        float r4 = j1 ? p[9] : p[4];

        float dx = r0 - t[0];
        float dy = r1 - t[1];
        float sw = sqrtf(fmaxf(r2, 0.0f)) - sqrtf(fmaxf(t[2], 0.0f));
        float sh = sqrtf(fmaxf(r3, 0.0f)) - sqrtf(fmaxf(t[3], 0.0f));
        float coord = dx * dx + dy * dy + sw * sw + sh * sh;
        float dc = r4 - max_iou;

        sum = 5.0f * coord + dc * dc + cls[tid];
    }

    // wave-64 reduction -> per-block atomic
    #pragma unroll
    for (int off = 32; off > 0; off >>= 1)
        sum += __shfl_down(sum, off, 64);
    if ((tid & 63) == 0) red[tid >> 6] = sum;
    __syncthreads();
    if (tid == 0) {
        float s = red[0] + red[1] + red[2] + red[3];
        atomicAdd(out, s * (1.0f / 16384.0f));
    }
}

extern "C" void kernel_launch(void* const* d_in, const int* in_sizes, int n_in,
                              void* d_out, int out_size, void* d_ws, size_t ws_size,
                              hipStream_t stream) {
    const float* pred = (const float*)d_in[0];
    const float* target = (const float*)d_in[1];
    float* out = (float*)d_out;
    // d_out is poisoned with 0xAA before every launch; we accumulate into it.
    hipMemsetAsync(out, 0, sizeof(float), stream);
    yolo_loss_kernel<<<NBLOCKS, TPB, 0, stream>>>(pred, target, out);
}